// Round 7
// baseline (377.537 us; speedup 1.0000x reference)
//
#include <hip/hip_runtime.h>
#include <math.h>

#define NB 32
#define NC 512
#define NF 1025

// ws layout (floats)
#define WS_MEAN 0
#define WS_SSTD 65536
#define WS_RSTD 131072
#define WS_GACC 196608
#define WS_WGT  229408                    // now: per-batch 32-float {sc[8], sidx[9]}
#define WS_PART 262208                    // optional: 2 × 65536 × {sum,sq}
#define WS_END_SPLIT (262208 + 262144)
// gating partials: 2048 blocks × 1025 floats (8.4 MB) — replaces atomics
#define WS_GPART WS_END_SPLIT
#define WS_GPART_FLOATS (NB * 64 * NF)
#define WS_END_GPART (WS_GPART + WS_GPART_FLOATS)

#define PIDX(a) ((a) + ((a) >> 4))

// LDS-only barrier: waits ds ops (lgkmcnt) but does NOT drain vmcnt, so global
// prefetch loads stay in flight across FFT stages. Measured equal to
// __syncthreads (r6) — kept since it is theoretically >= and verified.
__device__ __forceinline__ void lds_barrier() {
  __builtin_amdgcn_sched_barrier(0);
  asm volatile("s_waitcnt lgkmcnt(0)" ::: "memory");
  __builtin_amdgcn_s_barrier();
  __builtin_amdgcn_sched_barrier(0);
}

// ---------- Stockham radix-4 stage BODY (no barrier): 256 thr, 1024 pts ----------
__device__ __forceinline__ void stage4_body(const float* __restrict__ sr,
                                            const float* __restrict__ si,
                                            float* __restrict__ dr,
                                            float* __restrict__ di,
                                            const int ls, const float w1c, const float w1s,
                                            const bool fwd) {
  const int t = threadIdx.x;
  const int s = 1 << ls;
  const int q = t & (s - 1);
  const int p = t >> ls;
  const float ar = sr[PIDX(t)],       ai = si[PIDX(t)];
  const float br = sr[PIDX(t + 256)], bi = si[PIDX(t + 256)];
  const float cr = sr[PIDX(t + 512)], ci = si[PIDX(t + 512)];
  const float er = sr[PIDX(t + 768)], ei = si[PIDX(t + 768)];
  const float apcr = ar + cr, apci = ai + ci;
  const float amcr = ar - cr, amci = ai - ci;
  const float bpdr = br + er, bpdi = bi + ei;
  const float bmdr = br - er, bmdi = bi - ei;
  const float w2r = w1c * w1c - w1s * w1s, w2i = 2.0f * w1c * w1s;
  const float w3r = w2r * w1c - w2i * w1s, w3i = w2r * w1s + w2i * w1c;
  float u1r, u1i, u3r, u3i;
  if (fwd) {
    u1r = amcr + bmdi; u1i = amci - bmdr;
    u3r = amcr - bmdi; u3i = amci + bmdr;
  } else {
    u1r = amcr - bmdi; u1i = amci + bmdr;
    u3r = amcr + bmdi; u3i = amci - bmdr;
  }
  const float x0r = apcr + bpdr, x0i = apci + bpdi;
  const float v2r = apcr - bpdr, v2i = apci - bpdi;
  const float x1r = w1c * u1r - w1s * u1i, x1i = w1c * u1i + w1s * u1r;
  const float x2r = w2r * v2r - w2i * v2i, x2i = w2r * v2i + w2i * v2r;
  const float x3r = w3r * u3r - w3i * u3i, x3i = w3r * u3i + w3i * u3r;
  const int base = q + ((p << 2) << ls);
  dr[PIDX(base)] = x0r;             di[PIDX(base)] = x0i;
  dr[PIDX(base + s)] = x1r;         di[PIDX(base + s)] = x1i;
  dr[PIDX(base + 2 * s)] = x2r;     di[PIDX(base + 2 * s)] = x2i;
  dr[PIDX(base + 3 * s)] = x3r;     di[PIDX(base + 3 * s)] = x3i;
}

// wrapper with top LDS barrier
__device__ __forceinline__ void stage4(const float* __restrict__ sr,
                                       const float* __restrict__ si,
                                       float* __restrict__ dr,
                                       float* __restrict__ di,
                                       const int ls, const float w1c, const float w1s,
                                       const bool fwd) {
  lds_barrier();
  stage4_body(sr, si, dr, di, ls, w1c, w1s, fwd);
}

// Stage 0 fused from registers: inputs z[c] are the values at n = t + 256c.
__device__ __forceinline__ void stage0_reg(const float2 z0, const float2 z1,
                                           const float2 z2, const float2 z3,
                                           float* __restrict__ dr, float* __restrict__ di,
                                           const float w1c, const float w1s,
                                           const bool fwd) {
  const int t = threadIdx.x;
  const float apcr = z0.x + z2.x, apci = z0.y + z2.y;
  const float amcr = z0.x - z2.x, amci = z0.y - z2.y;
  const float bpdr = z1.x + z3.x, bpdi = z1.y + z3.y;
  const float bmdr = z1.x - z3.x, bmdi = z1.y - z3.y;
  const float w2r = w1c * w1c - w1s * w1s, w2i = 2.0f * w1c * w1s;
  const float w3r = w2r * w1c - w2i * w1s, w3i = w2r * w1s + w2i * w1c;
  float u1r, u1i, u3r, u3i;
  if (fwd) {
    u1r = amcr + bmdi; u1i = amci - bmdr;
    u3r = amcr - bmdi; u3i = amci + bmdr;
  } else {
    u1r = amcr - bmdi; u1i = amci + bmdr;
    u3r = amcr + bmdi; u3i = amci - bmdr;
  }
  const float x0r = apcr + bpdr, x0i = apci + bpdi;
  const float v2r = apcr - bpdr, v2i = apci - bpdi;
  const float x1r = w1c * u1r - w1s * u1i, x1i = w1c * u1i + w1s * u1r;
  const float x2r = w2r * v2r - w2i * v2i, x2i = w2r * v2i + w2i * v2r;
  const float x3r = w3r * u3r - w3i * u3i, x3i = w3r * u3i + w3i * u3r;
  const int base = t << 2;
  dr[PIDX(base)] = x0r;         di[PIDX(base)] = x0i;
  dr[PIDX(base + 1)] = x1r;     di[PIDX(base + 1)] = x1i;
  dr[PIDX(base + 2)] = x2r;     di[PIDX(base + 2)] = x2i;
  dr[PIDX(base + 3)] = x3r;     di[PIDX(base + 3)] = x3i;
}

// Last stage (ls=8) BODY: twiddles are identity; outputs in registers.
__device__ __forceinline__ void stage_nt_body(const float* __restrict__ sr,
                                              const float* __restrict__ si,
                                              float2& o0, float2& o1, float2& o2, float2& o3,
                                              const bool fwd) {
  const int t = threadIdx.x;
  const float ar = sr[PIDX(t)],       ai = si[PIDX(t)];
  const float br = sr[PIDX(t + 256)], bi = si[PIDX(t + 256)];
  const float cr = sr[PIDX(t + 512)], ci = si[PIDX(t + 512)];
  const float er = sr[PIDX(t + 768)], ei = si[PIDX(t + 768)];
  const float apcr = ar + cr, apci = ai + ci;
  const float amcr = ar - cr, amci = ai - ci;
  const float bpdr = br + er, bpdi = bi + ei;
  const float bmdr = br - er, bmdi = bi - ei;
  float u1r, u1i, u3r, u3i;
  if (fwd) {
    u1r = amcr + bmdi; u1i = amci - bmdr;
    u3r = amcr - bmdi; u3i = amci + bmdr;
  } else {
    u1r = amcr - bmdi; u1i = amci + bmdr;
    u3r = amcr + bmdi; u3i = amci - bmdr;
  }
  o0.x = apcr + bpdr;  o0.y = apci + bpdi;
  o1.x = u1r;          o1.y = u1i;
  o2.x = apcr - bpdr;  o2.y = apci - bpdi;
  o3.x = u3r;          o3.y = u3i;
}

__device__ __forceinline__ void stage_nt_reg(const float* __restrict__ sr,
                                             const float* __restrict__ si,
                                             float2& o0, float2& o1, float2& o2, float2& o3,
                                             const bool fwd) {
  lds_barrier();
  stage_nt_body(sr, si, o0, o1, o2, o3, fwd);
}

// Per-thread per-stage twiddles, computed once per kernel.
__device__ __forceinline__ void fft_twiddles(int t, float& c0, float& s0,
                                             float& c1, float& s1,
                                             float& c2, float& s2,
                                             float& c3, float& s3) {
  __sincosf(-0.00613592315f * (float)t, &s0, &c0);
  __sincosf(-0.02454369261f * (float)(t >> 2), &s1, &c1);
  __sincosf(-0.09817477042f * (float)(t >> 4), &s2, &c2);
  __sincosf(-0.39269908170f * (float)(t >> 6), &s3, &c3);
}

// ---------------- moments: single-pass fallback ----------------
__global__ __launch_bounds__(256) void kmoments(const float* __restrict__ x,
                                                float* __restrict__ ws) {
  const int b = blockIdx.x >> 3;
  const int l = ((blockIdx.x & 7) << 8) + threadIdx.x;
  const float* px = x + (size_t)b * (NC * 2048) + l;
  float sum = 0.f, sq = 0.f;
#pragma unroll 16
  for (int c = 0; c < NC; ++c) {
    float v = px[(size_t)c * 2048];
    sum += v;
    sq = fmaf(v, v, sq);
  }
  float mean = sum * (1.0f / 512.0f);
  float var = fmaf(-512.0f * mean, mean, sq) * (1.0f / 511.0f) + 1e-5f;
  float ss = sqrtf(var);
  int o = (b << 11) + l;
  ws[WS_MEAN + o] = mean;
  ws[WS_SSTD + o] = ss;
  ws[WS_RSTD + o] = 1.0f / ss;
}

// ---------------- moments: 2-way channel split ----------------
__global__ __launch_bounds__(256) void kmoments_part(const float* __restrict__ x,
                                                     float* __restrict__ ws) {
  const int b = blockIdx.x >> 3;
  const int l = ((blockIdx.x & 7) << 8) + threadIdx.x;
  const int half = blockIdx.y;
  const float* px = x + (size_t)b * (NC * 2048) + (size_t)(half * 256) * 2048 + l;
  float sum = 0.f, sq = 0.f;
#pragma unroll 16
  for (int c = 0; c < 256; ++c) {
    float v = px[(size_t)c * 2048];
    sum += v;
    sq = fmaf(v, v, sq);
  }
  int o = (b << 11) + l;
  float2* part = (float2*)(ws + WS_PART) + (half << 16) + o;
  float2 pv; pv.x = sum; pv.y = sq;
  *part = pv;
}

__global__ __launch_bounds__(256) void kmoments_fin(float* __restrict__ ws) {
  const int o = blockIdx.x * 256 + threadIdx.x;
  const float2* part = (const float2*)(ws + WS_PART);
  float2 p0 = part[o];
  float2 p1 = part[(1 << 16) + o];
  float sum = p0.x + p1.x, sq = p0.y + p1.y;
  float mean = sum * (1.0f / 512.0f);
  float var = fmaf(-512.0f * mean, mean, sq) * (1.0f / 511.0f) + 1e-5f;
  float ss = sqrtf(var);
  ws[WS_MEAN + o] = mean;
  ws[WS_SSTD + o] = ss;
  ws[WS_RSTD + o] = 1.0f / ss;
}

// ------- spectrum magnitudes: fwd FFT per row, per-thread register bins -------
// No spectrum cache this round (A/B: traffic vs compute). gpart != nullptr:
// per-block partial gating row instead of atomics.
__global__ __launch_bounds__(256) void kspec(const float* __restrict__ x,
                                             float* __restrict__ ws,
                                             float* __restrict__ gpart) {
  __shared__ float Ar[1088], Ai[1088], Br[1088], Bi[1088];
  const int tid = threadIdx.x;
  const int b = blockIdx.x >> 6;
  const int c0 = (blockIdx.x & 63) << 3;
  const float2* mean2 = (const float2*)(ws + WS_MEAN) + ((size_t)b << 10);
  const float2* rstd2 = (const float2*)(ws + WS_RSTD) + ((size_t)b << 10);
  float2 mv[4], rv[4];
#pragma unroll
  for (int j = 0; j < 4; ++j) {
    mv[j] = mean2[tid + (j << 8)];
    rv[j] = rstd2[tid + (j << 8)];
  }
  float w1s, w1c, w2s, w2c;
  __sincosf(-0.00306796158f * (float)tid, &w1s, &w1c);
  __sincosf(-0.00306796158f * (float)(tid + 256), &w2s, &w2c);
  float c0t, s0t, c1t, s1t, c2t, s2t, c3t, s3t;
  fft_twiddles(tid, c0t, s0t, c1t, s1t, c2t, s2t, c3t, s3t);
  float acc0 = 0.f, acc1 = 0.f, acc2 = 0.f, acc3 = 0.f, acc4 = 0.f;
  const float2* xrow = (const float2*)x + ((size_t)(b * NC + c0) << 10);
  float2 v[4];
#pragma unroll
  for (int j = 0; j < 4; ++j) v[j] = xrow[tid + (j << 8)];
  for (int r = 0; r < 8; ++r) {
    float2 zz[4];
#pragma unroll
    for (int j = 0; j < 4; ++j) {
      zz[j].x = (v[j].x - mv[j].x) * rv[j].x;
      zz[j].y = (v[j].y - mv[j].y) * rv[j].y;
    }
    if (r < 7) {
      const float2* nx = xrow + ((size_t)(r + 1) << 10);
#pragma unroll
      for (int j = 0; j < 4; ++j) v[j] = nx[tid + (j << 8)];
    }
    lds_barrier();  // previous iteration's readers of B are done
    stage0_reg(zz[0], zz[1], zz[2], zz[3], Br, Bi, c0t, s0t, true);
    stage4(Br, Bi, Ar, Ai, 2, c1t, s1t, true);
    stage4(Ar, Ai, Br, Bi, 4, c2t, s2t, true);
    stage4(Br, Bi, Ar, Ai, 6, c3t, s3t, true);
    float2 o0, o1, o2, o3;
    stage_nt_reg(Ar, Ai, o0, o1, o2, o3, true);
    Br[PIDX(tid)] = o0.x;        Bi[PIDX(tid)] = o0.y;
    Br[PIDX(tid + 256)] = o1.x;  Bi[PIDX(tid + 256)] = o1.y;
    Br[PIDX(tid + 512)] = o2.x;  Bi[PIDX(tid + 512)] = o2.y;
    Br[PIDX(tid + 768)] = o3.x;  Bi[PIDX(tid + 768)] = o3.y;
    lds_barrier();
    if (tid == 0) {
      float zr = Br[PIDX(0)], zi = Bi[PIDX(0)];
      acc0 += fabsf(zr + zi);         // bin 0
      acc1 += fabsf(zr - zi);         // bin 1024
      float mr = Br[PIDX(512)], mi = Bi[PIDX(512)];
      acc4 += sqrtf(mr * mr + mi * mi);  // bin 512
    } else {
      const int k = tid;
      float zkr = Br[PIDX(k)], zki = Bi[PIDX(k)];
      float zmr = Br[PIDX(1024 - k)], zmi = Bi[PIDX(1024 - k)];
      float Ar_ = 0.5f * (zkr + zmr), Ai_ = 0.5f * (zki - zmi);
      float Br_ = 0.5f * (zki + zmi), Bi_ = -0.5f * (zkr - zmr);
      float WBr = Br_ * w1c - Bi_ * w1s, WBi = Br_ * w1s + Bi_ * w1c;
      float Xr = Ar_ + WBr, Xi = Ai_ + WBi;
      float Yr = Ar_ - WBr, Yi = Ai_ - WBi;
      acc0 += sqrtf(Xr * Xr + Xi * Xi);     // bin k
      acc1 += sqrtf(Yr * Yr + Yi * Yi);     // bin 1024-k
    }
    {
      const int k = tid + 256;
      float zkr = Br[PIDX(k)], zki = Bi[PIDX(k)];
      float zmr = Br[PIDX(1024 - k)], zmi = Bi[PIDX(1024 - k)];
      float Ar_ = 0.5f * (zkr + zmr), Ai_ = 0.5f * (zki - zmi);
      float Br_ = 0.5f * (zki + zmi), Bi_ = -0.5f * (zkr - zmr);
      float WBr = Br_ * w2c - Bi_ * w2s, WBi = Br_ * w2s + Bi_ * w2c;
      float Xr = Ar_ + WBr, Xi = Ai_ + WBi;
      float Yr = Ar_ - WBr, Yi = Ai_ - WBi;
      acc2 += sqrtf(Xr * Xr + Xi * Xi);     // bin k
      acc3 += sqrtf(Yr * Yr + Yi * Yi);     // bin 1024-k
    }
  }
  if (gpart) {
    float* prow = gpart + (size_t)blockIdx.x * NF;
    prow[tid] = acc0;
    prow[1024 - tid] = acc1;
    prow[tid + 256] = acc2;
    prow[768 - tid] = acc3;
    if (tid == 0) prow[512] = acc4;
  } else {
    float* g = ws + WS_GACC + b * NF;
    atomicAdd(g + tid, acc0);
    atomicAdd(g + 1024 - tid, acc1);
    atomicAdd(g + tid + 256, acc2);
    atomicAdd(g + 768 - tid, acc3);
    if (tid == 0) atomicAdd(g + 512, acc4);
  }
}

// -------- gating: scores + band boundaries only (17 floats per batch) --------
// The per-bin weight expansion moved into kapply (8 predicated adds per bin),
// killing the 131 KB wgt round-trip and kgate's second f-loop.
__global__ __launch_bounds__(256) void kgate(float* __restrict__ ws,
                                             const float* __restrict__ gw,
                                             const float* __restrict__ gb,
                                             const float* __restrict__ bb,
                                             const float* __restrict__ gpart) {
  const float* gacc = ws + WS_GACC;
  const int b = blockIdx.x;
  const int tid = threadIdx.x;
  __shared__ float red[256];
  float acc[8];
#pragma unroll
  for (int e = 0; e < 8; ++e) acc[e] = 0.f;
  for (int f = tid; f < NF; f += 256) {
    float g;
    if (gpart) {
      const float* gp = gpart + (size_t)b * 64 * NF + f;
      g = 0.f;
#pragma unroll 8
      for (int j = 0; j < 64; ++j) g += gp[j * NF];
    } else {
      g = gacc[b * NF + f];
    }
    g *= (1.0f / 512.0f);
#pragma unroll
    for (int e = 0; e < 8; ++e) acc[e] = fmaf(g, gw[e * NF + f], acc[e]);
  }
  float sc[8];  // valid on tid==0
#pragma unroll
  for (int e = 0; e < 8; ++e) {
    __syncthreads();
    red[tid] = acc[e];
    __syncthreads();
    for (int s2 = 128; s2 > 0; s2 >>= 1) {
      if (tid < s2) red[tid] += red[tid + s2];
      __syncthreads();
    }
    if (tid == 0) sc[e] = red[0] + gb[e];
  }
  if (tid == 0) {
    float mx = sc[0];
    for (int e = 1; e < 8; ++e) mx = fmaxf(mx, sc[e]);
    float sum = 0.f;
    float ex[8];
    for (int e = 0; e < 8; ++e) { ex[e] = expf(sc[e] - mx); sum += ex[e]; }
    for (int e = 0; e < 8; ++e) sc[e] = ex[e] / sum;
    float sv[7];
    for (int i2 = 0; i2 < 7; ++i2) sv[i2] = 1.0f / (1.0f + expf(-bb[i2]));
    for (int i2 = 1; i2 < 7; ++i2) {
      float key = sv[i2];
      int j2 = i2 - 1;
      while (j2 >= 0 && sv[j2] > key) { sv[j2 + 1] = sv[j2]; --j2; }
      sv[j2 + 1] = key;
    }
    float* srow = ws + WS_WGT + (b << 5);
    for (int e = 0; e < 8; ++e) srow[e] = sc[e];
    srow[8] = 0.0f;
    for (int i2 = 0; i2 < 7; ++i2) srow[9 + i2] = (float)((int)(sv[i2] * 1025.0f));
    srow[16] = 1025.0f;
  }
}

// pair combine with spectral weights, in-place on (k, 1024-k)
__device__ __forceinline__ void combine_pair(float* __restrict__ zr_, float* __restrict__ zi_,
                                             int k, float wc, float ws_, float wk, float wmk) {
  const int ik = PIDX(k), im = PIDX(1024 - k);
  float zkr = zr_[ik], zki = zi_[ik];
  float zmr = zr_[im], zmi = zi_[im];
  float Ar_ = 0.5f * (zkr + zmr), Ai_ = 0.5f * (zki - zmi);
  float Br2 = 0.5f * (zki + zmi), Bi2 = -0.5f * (zkr - zmr);
  float WBr = Br2 * wc - Bi2 * ws_, WBi = Br2 * ws_ + Bi2 * wc;
  float Xr = Ar_ + WBr, Xi = Ai_ + WBi;    // X[k]
  float Xcr = Ar_ - WBr, Xci = Ai_ - WBi;  // conj(X[1024-k])
  float XpR = wk * Xr, XpI = wk * Xi;
  float XcpR = wmk * Xcr, XcpI = wmk * Xci;
  float Apr = 0.5f * (XpR + XcpR), Api = 0.5f * (XpI + XcpI);
  float Er = 0.5f * (XpR - XcpR), Ei = 0.5f * (XpI - XcpI);
  float Bpr = Er * wc + Ei * ws_;   // conj(W)*E
  float Bpi = Ei * wc - Er * ws_;
  zr_[ik] = Apr - Bpi;  zi_[ik] = Api + Bpr;
  zr_[im] = Apr + Bpi;  zi_[im] = Bpr - Api;
}

// weight-combine for a full spectrum held in (Br_,Bi_)
__device__ __forceinline__ void combine_all(float* __restrict__ Br_, float* __restrict__ Bi_,
                                            const int tid,
                                            const float w1c, const float w1s,
                                            const float w2c, const float w2s,
                                            const float wk1, const float wm1,
                                            const float wk2, const float wm2,
                                            const float wmid) {
  if (tid == 0) {
    float zr = Br_[PIDX(0)], zi = Bi_[PIDX(0)];
    float X0 = (zr + zi) * wk1;
    float XM = (zr - zi) * wm1;
    Br_[PIDX(0)] = 0.5f * (X0 + XM);
    Bi_[PIDX(0)] = 0.5f * (X0 - XM);
    Br_[PIDX(512)] *= wmid;
    Bi_[PIDX(512)] *= wmid;
  } else {
    combine_pair(Br_, Bi_, tid, w1c, w1s, wk1, wm1);
  }
  combine_pair(Br_, Bi_, tid + 256, w2c, w2s, wk2, wm2);
}

// ------- apply: fwd FFT, weight (inline from sc/sidx), inv FFT, store -------
__global__ __launch_bounds__(256) void kapply(const float* __restrict__ x,
                                              float* __restrict__ out,
                                              const float* __restrict__ ws) {
  __shared__ float Ar[1088], Ai[1088], Br[1088], Bi[1088];
  const int tid = threadIdx.x;
  const int b = blockIdx.x >> 9;
  const float2* mean2 = (const float2*)(ws + WS_MEAN) + ((size_t)b << 10);
  const float2* sstd2 = (const float2*)(ws + WS_SSTD) + ((size_t)b << 10);
  const float2* rstd2 = (const float2*)(ws + WS_RSTD) + ((size_t)b << 10);
  const float2* x2 = (const float2*)x + ((size_t)blockIdx.x << 10);
  // gate scores + band boundaries (17 floats, L2-broadcast)
  const float* srow = ws + WS_WGT + (b << 5);
  float scv[8], siv[9];
#pragma unroll
  for (int e = 0; e < 8; ++e) scv[e] = srow[e];
#pragma unroll
  for (int e = 0; e < 9; ++e) siv[e] = srow[8 + e];
  // per-bin weight: sum of scores of experts whose band contains f
#define BANDW(ff, dst) { float wv = 0.f; \
    _Pragma("unroll") \
    for (int e = 0; e < 8; ++e) \
      wv += ((ff) >= siv[e] && (ff) < siv[e + 1]) ? scv[e] : 0.f; \
    dst = wv; }
  float wk1, wm1, wk2, wm2, wmid;
  BANDW((float)tid, wk1);
  BANDW((float)(1024 - tid), wm1);
  BANDW((float)(tid + 256), wk2);
  BANDW((float)(768 - tid), wm2);
  BANDW(512.0f, wmid);
#undef BANDW
  float w1s, w1c, w2s, w2c;
  __sincosf(-0.00306796158f * (float)tid, &w1s, &w1c);
  __sincosf(-0.00306796158f * (float)(tid + 256), &w2s, &w2c);
  float c0t, s0t, c1t, s1t, c2t, s2t, c3t, s3t;
  fft_twiddles(tid, c0t, s0t, c1t, s1t, c2t, s2t, c3t, s3t);
  float2 mv[4], rv[4], ssv[4];
#pragma unroll
  for (int j = 0; j < 4; ++j) {
    mv[j] = mean2[tid + (j << 8)];
    rv[j] = rstd2[tid + (j << 8)];
    ssv[j] = sstd2[tid + (j << 8)];
  }
  float2 zz[4];
#pragma unroll
  for (int j = 0; j < 4; ++j) {
    float2 v = x2[tid + (j << 8)];
    zz[j].x = (v.x - mv[j].x) * rv[j].x;
    zz[j].y = (v.y - mv[j].y) * rv[j].y;
  }
  stage0_reg(zz[0], zz[1], zz[2], zz[3], Br, Bi, c0t, s0t, true);
  stage4(Br, Bi, Ar, Ai, 2, c1t, s1t, true);
  stage4(Ar, Ai, Br, Bi, 4, c2t, s2t, true);
  stage4(Br, Bi, Ar, Ai, 6, c3t, s3t, true);
  float2 f0, f1, f2, f3;
  stage_nt_reg(Ar, Ai, f0, f1, f2, f3, true);
  Br[PIDX(tid)] = f0.x;        Bi[PIDX(tid)] = f0.y;
  Br[PIDX(tid + 256)] = f1.x;  Bi[PIDX(tid + 256)] = f1.y;
  Br[PIDX(tid + 512)] = f2.x;  Bi[PIDX(tid + 512)] = f2.y;
  Br[PIDX(tid + 768)] = f3.x;  Bi[PIDX(tid + 768)] = f3.y;
  lds_barrier();  // B complete before cross-thread pair access
  combine_all(Br, Bi, tid, w1c, w1s, w2c, w2s, wk1, wm1, wk2, wm2, wmid);
  stage4(Br, Bi, Ar, Ai, 0, c0t, -s0t, false);
  stage4(Ar, Ai, Br, Bi, 2, c1t, -s1t, false);
  stage4(Br, Bi, Ar, Ai, 4, c2t, -s2t, false);
  stage4(Ar, Ai, Br, Bi, 6, c3t, -s3t, false);
  float2 o0, o1, o2, o3;
  stage_nt_reg(Br, Bi, o0, o1, o2, o3, false);
  const float inv = 1.0f / 1024.0f;
  float2* out2 = (float2*)out + ((size_t)blockIdx.x << 10);
  float2 oo;
  oo.x = fmaf(o0.x * inv, ssv[0].x, mv[0].x);
  oo.y = fmaf(o0.y * inv, ssv[0].y, mv[0].y);
  out2[tid] = oo;
  oo.x = fmaf(o1.x * inv, ssv[1].x, mv[1].x);
  oo.y = fmaf(o1.y * inv, ssv[1].y, mv[1].y);
  out2[tid + 256] = oo;
  oo.x = fmaf(o2.x * inv, ssv[2].x, mv[2].x);
  oo.y = fmaf(o2.y * inv, ssv[2].y, mv[2].y);
  out2[tid + 512] = oo;
  oo.x = fmaf(o3.x * inv, ssv[3].x, mv[3].x);
  oo.y = fmaf(o3.y * inv, ssv[3].y, mv[3].y);
  out2[tid + 768] = oo;
}

extern "C" void kernel_launch(void* const* d_in, const int* in_sizes, int n_in,
                              void* d_out, int out_size, void* d_ws, size_t ws_size,
                              hipStream_t stream) {
  const float* x = (const float*)d_in[0];
  const float* bb = (const float*)d_in[1];
  const float* gw = (const float*)d_in[2];
  const float* gb = (const float*)d_in[3];
  float* ws = (float*)d_ws;
  float* out = (float*)d_out;

  const bool split = ws_size >= (size_t)WS_END_SPLIT * sizeof(float);
  const bool part = ws_size >= (size_t)WS_END_GPART * sizeof(float);

  if (!part) {
    hipMemsetAsync((char*)d_ws + WS_GACC * sizeof(float), 0, (NB * NF) * sizeof(float), stream);
  }
  if (split) {
    kmoments_part<<<dim3(NB * 8, 2), dim3(256), 0, stream>>>(x, ws);
    kmoments_fin<<<dim3(256), dim3(256), 0, stream>>>(ws);
  } else {
    kmoments<<<dim3(NB * 8), dim3(256), 0, stream>>>(x, ws);
  }
  kspec<<<dim3(NB * 64), dim3(256), 0, stream>>>(x, ws,
      part ? (ws + WS_GPART) : nullptr);
  kgate<<<dim3(NB), dim3(256), 0, stream>>>(ws, gw, gb, bb,
      part ? (ws + WS_GPART) : nullptr);
  kapply<<<dim3(NB * NC), dim3(256), 0, stream>>>(x, out, ws);
}

// Round 8
// 345.681 us; speedup vs baseline: 1.0922x; 1.0922x over previous
//
#include <hip/hip_runtime.h>
#include <math.h>

#define NB 32
#define NC 512
#define NF 1025

// ws layout (floats)
#define WS_MEAN 0
#define WS_SSTD 65536
#define WS_RSTD 131072
#define WS_GACC 196608
#define WS_WGT  229408                    // per-batch 32-float {sc[8], sidx[9]}
#define WS_PART 262208                    // optional: 2 × 65536 × {sum,sq}
#define WS_END_SPLIT (262208 + 262144)
// cached spectrum: NB*NC rows × 1024 complex = 33,554,432 floats (134 MB)
#define WS_SPEC WS_END_SPLIT
#define WS_SPEC_FLOATS (NB * NC * 2048)
#define WS_END_CACHE (WS_SPEC + WS_SPEC_FLOATS)
// gating partials: 2048 blocks × 1025 floats (8.4 MB) — replaces atomics
#define WS_GPART WS_END_CACHE
#define WS_GPART_FLOATS (NB * 64 * NF)
#define WS_END_GPART (WS_GPART + WS_GPART_FLOATS)

// float2 (complex) LDS skew: n + 2*(n>>4). Verified by hand:
//  - b64 stride-1 reads (n = t+256c): conflict-free per 16-lane quarter
//  - ls=0 b128 writes (2 per thread, contiguous float2 x4): conflict-free
//  - ls=4 / ls=6 strided b64 writes: conflict-free
//  - ls=2 strided b64 writes: worst-case 2-way
// Replaces split-r/i b32 layout whose (n + n>>4) skew measured 2.08e7
// conflict-cycles per kapply dispatch (r7 PMC).
#define P2(a) ((a) + 2 * ((a) >> 4))
// max index P2(1023) = 1149 -> 1152 float2 = 9216 B per buffer

// LDS-only barrier (lgkm wait, no vmcnt drain). Measured parity with
// __syncthreads (r6); kept because it is theoretically >=.
__device__ __forceinline__ void lds_barrier() {
  __builtin_amdgcn_sched_barrier(0);
  asm volatile("s_waitcnt lgkmcnt(0)" ::: "memory");
  __builtin_amdgcn_s_barrier();
  __builtin_amdgcn_sched_barrier(0);
}

// per-stage twiddles (w1, w2=w1^2, w3=w1^3) hoisted out of the stage body
struct Tw { float c1, s1, c2, s2, c3, s3; };
__device__ __forceinline__ Tw make_tw(float c, float s) {
  Tw t;
  t.c1 = c; t.s1 = s;
  t.c2 = c * c - s * s;      t.s2 = 2.0f * c * s;
  t.c3 = t.c2 * c - t.s2 * s; t.s3 = t.c2 * s + t.s2 * c;
  return t;
}
__device__ __forceinline__ Tw conj_tw(Tw t) { t.s1 = -t.s1; t.s2 = -t.s2; t.s3 = -t.s3; return t; }

// ---------- Stockham radix-4 stage BODY (no barrier): 256 thr, 1024 pts ----------
// Reads at t+256c (thread-private); writes at q+s*(4p+c), P2-skewed.
__device__ __forceinline__ void stage4_body(const float2* __restrict__ src,
                                            float2* __restrict__ dst,
                                            const int ls, const Tw tw, const bool fwd) {
  const int t = threadIdx.x;
  const int s = 1 << ls;
  const int q = t & (s - 1);
  const int p = t >> ls;
  const float2 a = src[P2(t)];
  const float2 b = src[P2(t + 256)];
  const float2 c = src[P2(t + 512)];
  const float2 e = src[P2(t + 768)];
  const float apcr = a.x + c.x, apci = a.y + c.y;
  const float amcr = a.x - c.x, amci = a.y - c.y;
  const float bpdr = b.x + e.x, bpdi = b.y + e.y;
  const float bmdr = b.x - e.x, bmdi = b.y - e.y;
  float u1r, u1i, u3r, u3i;
  if (fwd) {
    u1r = amcr + bmdi; u1i = amci - bmdr;
    u3r = amcr - bmdi; u3i = amci + bmdr;
  } else {
    u1r = amcr - bmdi; u1i = amci + bmdr;
    u3r = amcr + bmdi; u3i = amci - bmdr;
  }
  const float v2r = apcr - bpdr, v2i = apci - bpdi;
  const int base = q + ((p << 2) << ls);
  dst[P2(base)] = make_float2(apcr + bpdr, apci + bpdi);
  dst[P2(base + s)] = make_float2(tw.c1 * u1r - tw.s1 * u1i, tw.c1 * u1i + tw.s1 * u1r);
  dst[P2(base + 2 * s)] = make_float2(tw.c2 * v2r - tw.s2 * v2i, tw.c2 * v2i + tw.s2 * v2r);
  dst[P2(base + 3 * s)] = make_float2(tw.c3 * u3r - tw.s3 * u3i, tw.c3 * u3i + tw.s3 * u3r);
}

__device__ __forceinline__ void stage4(const float2* __restrict__ src,
                                       float2* __restrict__ dst,
                                       const int ls, const Tw tw, const bool fwd) {
  lds_barrier();
  stage4_body(src, dst, ls, tw, fwd);
}

// Stage 0 fused from registers; writes 4 contiguous float2 (2 x b128).
__device__ __forceinline__ void stage0_reg(const float2 z0, const float2 z1,
                                           const float2 z2, const float2 z3,
                                           float2* __restrict__ dst,
                                           const Tw tw, const bool fwd) {
  const int t = threadIdx.x;
  const float apcr = z0.x + z2.x, apci = z0.y + z2.y;
  const float amcr = z0.x - z2.x, amci = z0.y - z2.y;
  const float bpdr = z1.x + z3.x, bpdi = z1.y + z3.y;
  const float bmdr = z1.x - z3.x, bmdi = z1.y - z3.y;
  float u1r, u1i, u3r, u3i;
  if (fwd) {
    u1r = amcr + bmdi; u1i = amci - bmdr;
    u3r = amcr - bmdi; u3i = amci + bmdr;
  } else {
    u1r = amcr - bmdi; u1i = amci + bmdr;
    u3r = amcr + bmdi; u3i = amci - bmdr;
  }
  const float v2r = apcr - bpdr, v2i = apci - bpdi;
  // elements 4t..4t+3 never cross a 16-boundary, so P2 keeps them contiguous
  float4* d4 = (float4*)&dst[P2(t << 2)];
  d4[0] = make_float4(apcr + bpdr, apci + bpdi,
                      tw.c1 * u1r - tw.s1 * u1i, tw.c1 * u1i + tw.s1 * u1r);
  d4[1] = make_float4(tw.c2 * v2r - tw.s2 * v2i, tw.c2 * v2i + tw.s2 * v2r,
                      tw.c3 * u3r - tw.s3 * u3i, tw.c3 * u3i + tw.s3 * u3r);
}

// Last stage (ls=8): twiddles identity; outputs in registers.
__device__ __forceinline__ void stage_nt_body(const float2* __restrict__ src,
                                              float2& o0, float2& o1, float2& o2, float2& o3,
                                              const bool fwd) {
  const int t = threadIdx.x;
  const float2 a = src[P2(t)];
  const float2 b = src[P2(t + 256)];
  const float2 c = src[P2(t + 512)];
  const float2 e = src[P2(t + 768)];
  const float apcr = a.x + c.x, apci = a.y + c.y;
  const float amcr = a.x - c.x, amci = a.y - c.y;
  const float bpdr = b.x + e.x, bpdi = b.y + e.y;
  const float bmdr = b.x - e.x, bmdi = b.y - e.y;
  float u1r, u1i, u3r, u3i;
  if (fwd) {
    u1r = amcr + bmdi; u1i = amci - bmdr;
    u3r = amcr - bmdi; u3i = amci + bmdr;
  } else {
    u1r = amcr - bmdi; u1i = amci + bmdr;
    u3r = amcr + bmdi; u3i = amci - bmdr;
  }
  o0 = make_float2(apcr + bpdr, apci + bpdi);
  o1 = make_float2(u1r, u1i);
  o2 = make_float2(apcr - bpdr, apci - bpdi);
  o3 = make_float2(u3r, u3i);
}

__device__ __forceinline__ void stage_nt_reg(const float2* __restrict__ src,
                                             float2& o0, float2& o1, float2& o2, float2& o3,
                                             const bool fwd) {
  lds_barrier();
  stage_nt_body(src, o0, o1, o2, o3, fwd);
}

// 4 per-stage twiddle sets, computed once per kernel
__device__ __forceinline__ void fft_tws(int t, Tw& t0, Tw& t1, Tw& t2, Tw& t3) {
  float c, s;
  __sincosf(-0.00613592315f * (float)t, &s, &c);        t0 = make_tw(c, s);
  __sincosf(-0.02454369261f * (float)(t >> 2), &s, &c); t1 = make_tw(c, s);
  __sincosf(-0.09817477042f * (float)(t >> 4), &s, &c); t2 = make_tw(c, s);
  __sincosf(-0.39269908170f * (float)(t >> 6), &s, &c); t3 = make_tw(c, s);
}

// ---------------- moments ----------------
__global__ __launch_bounds__(256) void kmoments(const float* __restrict__ x,
                                                float* __restrict__ ws) {
  const int b = blockIdx.x >> 3;
  const int l = ((blockIdx.x & 7) << 8) + threadIdx.x;
  const float* px = x + (size_t)b * (NC * 2048) + l;
  float sum = 0.f, sq = 0.f;
#pragma unroll 16
  for (int c = 0; c < NC; ++c) {
    float v = px[(size_t)c * 2048];
    sum += v;
    sq = fmaf(v, v, sq);
  }
  float mean = sum * (1.0f / 512.0f);
  float var = fmaf(-512.0f * mean, mean, sq) * (1.0f / 511.0f) + 1e-5f;
  float ss = sqrtf(var);
  int o = (b << 11) + l;
  ws[WS_MEAN + o] = mean;
  ws[WS_SSTD + o] = ss;
  ws[WS_RSTD + o] = 1.0f / ss;
}

__global__ __launch_bounds__(256) void kmoments_part(const float* __restrict__ x,
                                                     float* __restrict__ ws) {
  const int b = blockIdx.x >> 3;
  const int l = ((blockIdx.x & 7) << 8) + threadIdx.x;
  const int half = blockIdx.y;
  const float* px = x + (size_t)b * (NC * 2048) + (size_t)(half * 256) * 2048 + l;
  float sum = 0.f, sq = 0.f;
#pragma unroll 16
  for (int c = 0; c < 256; ++c) {
    float v = px[(size_t)c * 2048];
    sum += v;
    sq = fmaf(v, v, sq);
  }
  int o = (b << 11) + l;
  float2* part = (float2*)(ws + WS_PART) + (half << 16) + o;
  float2 pv; pv.x = sum; pv.y = sq;
  *part = pv;
}

__global__ __launch_bounds__(256) void kmoments_fin(float* __restrict__ ws) {
  const int o = blockIdx.x * 256 + threadIdx.x;
  const float2* part = (const float2*)(ws + WS_PART);
  float2 p0 = part[o];
  float2 p1 = part[(1 << 16) + o];
  float sum = p0.x + p1.x, sq = p0.y + p1.y;
  float mean = sum * (1.0f / 512.0f);
  float var = fmaf(-512.0f * mean, mean, sq) * (1.0f / 511.0f) + 1e-5f;
  float ss = sqrtf(var);
  ws[WS_MEAN + o] = mean;
  ws[WS_SSTD + o] = ss;
  ws[WS_RSTD + o] = 1.0f / ss;
}

// ------- spectrum magnitudes + Z cache -------
__global__ __launch_bounds__(256) void kspec(const float* __restrict__ x,
                                             float* __restrict__ ws,
                                             float2* __restrict__ zout,
                                             float* __restrict__ gpart) {
  __shared__ __align__(16) float2 A[1152], B[1152];
  const int tid = threadIdx.x;
  const int b = blockIdx.x >> 6;
  const int c0 = (blockIdx.x & 63) << 3;
  const float2* mean2 = (const float2*)(ws + WS_MEAN) + ((size_t)b << 10);
  const float2* rstd2 = (const float2*)(ws + WS_RSTD) + ((size_t)b << 10);
  float2 mv[4], rv[4];
#pragma unroll
  for (int j = 0; j < 4; ++j) {
    mv[j] = mean2[tid + (j << 8)];
    rv[j] = rstd2[tid + (j << 8)];
  }
  float w1s, w1c, w2s, w2c;
  __sincosf(-0.00306796158f * (float)tid, &w1s, &w1c);
  __sincosf(-0.00306796158f * (float)(tid + 256), &w2s, &w2c);
  Tw t0, t1, t2, t3;
  fft_tws(tid, t0, t1, t2, t3);
  float acc0 = 0.f, acc1 = 0.f, acc2 = 0.f, acc3 = 0.f, acc4 = 0.f;
  const float2* xrow = (const float2*)x + ((size_t)(b * NC + c0) << 10);
  float2 v[4];
#pragma unroll
  for (int j = 0; j < 4; ++j) v[j] = xrow[tid + (j << 8)];
  for (int r = 0; r < 8; ++r) {
    float2 zz[4];
#pragma unroll
    for (int j = 0; j < 4; ++j) {
      zz[j].x = (v[j].x - mv[j].x) * rv[j].x;
      zz[j].y = (v[j].y - mv[j].y) * rv[j].y;
    }
    if (r < 7) {
      const float2* nx = xrow + ((size_t)(r + 1) << 10);
#pragma unroll
      for (int j = 0; j < 4; ++j) v[j] = nx[tid + (j << 8)];
    }
    lds_barrier();  // prev iteration's mag reads of B done
    stage0_reg(zz[0], zz[1], zz[2], zz[3], B, t0, true);
    stage4(B, A, 2, t1, true);
    stage4(A, B, 4, t2, true);
    stage4(B, A, 6, t3, true);
    float2 o0, o1, o2, o3;
    stage_nt_reg(A, o0, o1, o2, o3, true);
    B[P2(tid)] = o0;
    B[P2(tid + 256)] = o1;
    B[P2(tid + 512)] = o2;
    B[P2(tid + 768)] = o3;
    lds_barrier();
    if (zout) {  // spectrum cache straight from registers
      float2* zrow = zout + ((size_t)(b * NC + c0 + r) << 10);
      zrow[tid] = o0;
      zrow[tid + 256] = o1;
      zrow[tid + 512] = o2;
      zrow[tid + 768] = o3;
    }
    if (tid == 0) {
      float2 z0 = B[P2(0)];
      acc0 += fabsf(z0.x + z0.y);        // bin 0
      acc1 += fabsf(z0.x - z0.y);        // bin 1024
      float2 zm = B[P2(512)];
      acc4 += sqrtf(zm.x * zm.x + zm.y * zm.y);  // bin 512
    } else {
      const int k = tid;
      float2 zk = B[P2(k)], zm = B[P2(1024 - k)];
      float Ar_ = 0.5f * (zk.x + zm.x), Ai_ = 0.5f * (zk.y - zm.y);
      float Bq = 0.5f * (zk.y + zm.y), Bi2 = -0.5f * (zk.x - zm.x);
      float WBr = Bq * w1c - Bi2 * w1s, WBi = Bq * w1s + Bi2 * w1c;
      float Xr = Ar_ + WBr, Xi = Ai_ + WBi;
      float Yr = Ar_ - WBr, Yi = Ai_ - WBi;
      acc0 += sqrtf(Xr * Xr + Xi * Xi);
      acc1 += sqrtf(Yr * Yr + Yi * Yi);
    }
    {
      const int k = tid + 256;
      float2 zk = B[P2(k)], zm = B[P2(1024 - k)];
      float Ar_ = 0.5f * (zk.x + zm.x), Ai_ = 0.5f * (zk.y - zm.y);
      float Bq = 0.5f * (zk.y + zm.y), Bi2 = -0.5f * (zk.x - zm.x);
      float WBr = Bq * w2c - Bi2 * w2s, WBi = Bq * w2s + Bi2 * w2c;
      float Xr = Ar_ + WBr, Xi = Ai_ + WBi;
      float Yr = Ar_ - WBr, Yi = Ai_ - WBi;
      acc2 += sqrtf(Xr * Xr + Xi * Xi);
      acc3 += sqrtf(Yr * Yr + Yi * Yi);
    }
  }
  if (gpart) {
    float* prow = gpart + (size_t)blockIdx.x * NF;
    prow[tid] = acc0;
    prow[1024 - tid] = acc1;
    prow[tid + 256] = acc2;
    prow[768 - tid] = acc3;
    if (tid == 0) prow[512] = acc4;
  } else {
    float* g = ws + WS_GACC + b * NF;
    atomicAdd(g + tid, acc0);
    atomicAdd(g + 1024 - tid, acc1);
    atomicAdd(g + tid + 256, acc2);
    atomicAdd(g + 768 - tid, acc3);
    if (tid == 0) atomicAdd(g + 512, acc4);
  }
}

// -------- gating: scores + band boundaries (17 floats per batch) --------
__global__ __launch_bounds__(256) void kgate(float* __restrict__ ws,
                                             const float* __restrict__ gw,
                                             const float* __restrict__ gb,
                                             const float* __restrict__ bb,
                                             const float* __restrict__ gpart) {
  const float* gacc = ws + WS_GACC;
  const int b = blockIdx.x;
  const int tid = threadIdx.x;
  __shared__ float red[256];
  float acc[8];
#pragma unroll
  for (int e = 0; e < 8; ++e) acc[e] = 0.f;
  for (int f = tid; f < NF; f += 256) {
    float g;
    if (gpart) {
      const float* gp = gpart + (size_t)b * 64 * NF + f;
      g = 0.f;
#pragma unroll 8
      for (int j = 0; j < 64; ++j) g += gp[j * NF];
    } else {
      g = gacc[b * NF + f];
    }
    g *= (1.0f / 512.0f);
#pragma unroll
    for (int e = 0; e < 8; ++e) acc[e] = fmaf(g, gw[e * NF + f], acc[e]);
  }
  float sc[8];
#pragma unroll
  for (int e = 0; e < 8; ++e) {
    __syncthreads();
    red[tid] = acc[e];
    __syncthreads();
    for (int s2 = 128; s2 > 0; s2 >>= 1) {
      if (tid < s2) red[tid] += red[tid + s2];
      __syncthreads();
    }
    if (tid == 0) sc[e] = red[0] + gb[e];
  }
  if (tid == 0) {
    float mx = sc[0];
    for (int e = 1; e < 8; ++e) mx = fmaxf(mx, sc[e]);
    float sum = 0.f;
    float ex[8];
    for (int e = 0; e < 8; ++e) { ex[e] = expf(sc[e] - mx); sum += ex[e]; }
    for (int e = 0; e < 8; ++e) sc[e] = ex[e] / sum;
    float sv[7];
    for (int i2 = 0; i2 < 7; ++i2) sv[i2] = 1.0f / (1.0f + expf(-bb[i2]));
    for (int i2 = 1; i2 < 7; ++i2) {
      float key = sv[i2];
      int j2 = i2 - 1;
      while (j2 >= 0 && sv[j2] > key) { sv[j2 + 1] = sv[j2]; --j2; }
      sv[j2 + 1] = key;
    }
    float* srow = ws + WS_WGT + (b << 5);
    for (int e = 0; e < 8; ++e) srow[e] = sc[e];
    srow[8] = 0.0f;
    for (int i2 = 0; i2 < 7; ++i2) srow[9 + i2] = (float)((int)(sv[i2] * 1025.0f));
    srow[16] = 1025.0f;
  }
}

// pair combine with spectral weights, in-place on (k, 1024-k)
__device__ __forceinline__ void combine_pair(float2* __restrict__ z,
                                             int k, float wc, float ws_, float wk, float wmk) {
  const int ik = P2(k), im = P2(1024 - k);
  float2 zk = z[ik], zm = z[im];
  float Ar_ = 0.5f * (zk.x + zm.x), Ai_ = 0.5f * (zk.y - zm.y);
  float Br2 = 0.5f * (zk.y + zm.y), Bi2 = -0.5f * (zk.x - zm.x);
  float WBr = Br2 * wc - Bi2 * ws_, WBi = Br2 * ws_ + Bi2 * wc;
  float Xr = Ar_ + WBr, Xi = Ai_ + WBi;    // X[k]
  float Xcr = Ar_ - WBr, Xci = Ai_ - WBi;  // conj(X[1024-k])
  float XpR = wk * Xr, XpI = wk * Xi;
  float XcpR = wmk * Xcr, XcpI = wmk * Xci;
  float Apr = 0.5f * (XpR + XcpR), Api = 0.5f * (XpI + XcpI);
  float Er = 0.5f * (XpR - XcpR), Ei = 0.5f * (XpI - XcpI);
  float Bpr = Er * wc + Ei * ws_;   // conj(W)*E
  float Bpi = Ei * wc - Er * ws_;
  z[ik] = make_float2(Apr - Bpi, Api + Bpr);
  z[im] = make_float2(Apr + Bpi, Bpr - Api);
}

__device__ __forceinline__ void combine_all(float2* __restrict__ z, const int tid,
                                            const float w1c, const float w1s,
                                            const float w2c, const float w2s,
                                            const float wk1, const float wm1,
                                            const float wk2, const float wm2,
                                            const float wmid) {
  if (tid == 0) {
    float2 z0 = z[P2(0)];
    float X0 = (z0.x + z0.y) * wk1;
    float XM = (z0.x - z0.y) * wm1;
    z[P2(0)] = make_float2(0.5f * (X0 + XM), 0.5f * (X0 - XM));
    float2 zm = z[P2(512)];
    z[P2(512)] = make_float2(zm.x * wmid, zm.y * wmid);
  } else {
    combine_pair(z, tid, w1c, w1s, wk1, wm1);
  }
  combine_pair(z, tid + 256, w2c, w2s, wk2, wm2);
}

// per-bin gate weight from sc/sidx (loaded per-thread)
#define BANDW(ff, siv, scv, dst) { float wv = 0.f; \
    _Pragma("unroll") \
    for (int e = 0; e < 8; ++e) \
      wv += ((ff) >= siv[e] && (ff) < siv[e + 1]) ? scv[e] : 0.f; \
    dst = wv; }

// ------- apply (fallback): fwd FFT, weight, inv FFT, de-normalize, store -------
__global__ __launch_bounds__(256) void kapply(const float* __restrict__ x,
                                              float* __restrict__ out,
                                              const float* __restrict__ ws) {
  __shared__ __align__(16) float2 A[1152], B[1152];
  const int tid = threadIdx.x;
  const int b = blockIdx.x >> 9;
  const float2* mean2 = (const float2*)(ws + WS_MEAN) + ((size_t)b << 10);
  const float2* sstd2 = (const float2*)(ws + WS_SSTD) + ((size_t)b << 10);
  const float2* rstd2 = (const float2*)(ws + WS_RSTD) + ((size_t)b << 10);
  const float2* x2 = (const float2*)x + ((size_t)blockIdx.x << 10);
  const float* srow = ws + WS_WGT + (b << 5);
  float scv[8], siv[9];
#pragma unroll
  for (int e = 0; e < 8; ++e) scv[e] = srow[e];
#pragma unroll
  for (int e = 0; e < 9; ++e) siv[e] = srow[8 + e];
  float wk1, wm1, wk2, wm2, wmid;
  BANDW((float)tid, siv, scv, wk1);
  BANDW((float)(1024 - tid), siv, scv, wm1);
  BANDW((float)(tid + 256), siv, scv, wk2);
  BANDW((float)(768 - tid), siv, scv, wm2);
  BANDW(512.0f, siv, scv, wmid);
  float w1s, w1c, w2s, w2c;
  __sincosf(-0.00306796158f * (float)tid, &w1s, &w1c);
  __sincosf(-0.00306796158f * (float)(tid + 256), &w2s, &w2c);
  Tw t0, t1, t2, t3;
  fft_tws(tid, t0, t1, t2, t3);
  const Tw i0 = conj_tw(t0), i1 = conj_tw(t1), i2 = conj_tw(t2), i3 = conj_tw(t3);
  float2 mv[4], rv[4], ssv[4];
#pragma unroll
  for (int j = 0; j < 4; ++j) {
    mv[j] = mean2[tid + (j << 8)];
    rv[j] = rstd2[tid + (j << 8)];
    ssv[j] = sstd2[tid + (j << 8)];
  }
  float2 zz[4];
#pragma unroll
  for (int j = 0; j < 4; ++j) {
    float2 v = x2[tid + (j << 8)];
    zz[j].x = (v.x - mv[j].x) * rv[j].x;
    zz[j].y = (v.y - mv[j].y) * rv[j].y;
  }
  stage0_reg(zz[0], zz[1], zz[2], zz[3], B, t0, true);
  stage4(B, A, 2, t1, true);
  stage4(A, B, 4, t2, true);
  stage4(B, A, 6, t3, true);
  float2 f0, f1, f2, f3;
  stage_nt_reg(A, f0, f1, f2, f3, true);
  B[P2(tid)] = f0;
  B[P2(tid + 256)] = f1;
  B[P2(tid + 512)] = f2;
  B[P2(tid + 768)] = f3;
  lds_barrier();
  combine_all(B, tid, w1c, w1s, w2c, w2s, wk1, wm1, wk2, wm2, wmid);
  stage4(B, A, 0, i0, false);
  stage4(A, B, 2, i1, false);
  stage4(B, A, 4, i2, false);
  stage4(A, B, 6, i3, false);
  float2 o0, o1, o2, o3;
  stage_nt_reg(B, o0, o1, o2, o3, false);
  const float inv = 1.0f / 1024.0f;
  float2* out2 = (float2*)out + ((size_t)blockIdx.x << 10);
  float2 oo;
  oo.x = fmaf(o0.x * inv, ssv[0].x, mv[0].x);
  oo.y = fmaf(o0.y * inv, ssv[0].y, mv[0].y);
  out2[tid] = oo;
  oo.x = fmaf(o1.x * inv, ssv[1].x, mv[1].x);
  oo.y = fmaf(o1.y * inv, ssv[1].y, mv[1].y);
  out2[tid + 256] = oo;
  oo.x = fmaf(o2.x * inv, ssv[2].x, mv[2].x);
  oo.y = fmaf(o2.y * inv, ssv[2].y, mv[2].y);
  out2[tid + 512] = oo;
  oo.x = fmaf(o3.x * inv, ssv[3].x, mv[3].x);
  oo.y = fmaf(o3.y * inv, ssv[3].y, mv[3].y);
  out2[tid + 768] = oo;
}

// ------- apply (cached): load Z, weight, inv FFT, de-normalize, store -------
__global__ __launch_bounds__(256) void kapply_z(const float2* __restrict__ z,
                                                float* __restrict__ out,
                                                const float* __restrict__ ws) {
  __shared__ __align__(16) float2 A[1152], B[1152];
  const int tid = threadIdx.x;
  const int b = blockIdx.x >> 9;
  const float2* mean2 = (const float2*)(ws + WS_MEAN) + ((size_t)b << 10);
  const float2* sstd2 = (const float2*)(ws + WS_SSTD) + ((size_t)b << 10);
  const float* srow = ws + WS_WGT + (b << 5);
  float scv[8], siv[9];
#pragma unroll
  for (int e = 0; e < 8; ++e) scv[e] = srow[e];
#pragma unroll
  for (int e = 0; e < 9; ++e) siv[e] = srow[8 + e];
  float wk1, wm1, wk2, wm2, wmid;
  BANDW((float)tid, siv, scv, wk1);
  BANDW((float)(1024 - tid), siv, scv, wm1);
  BANDW((float)(tid + 256), siv, scv, wk2);
  BANDW((float)(768 - tid), siv, scv, wm2);
  BANDW(512.0f, siv, scv, wmid);
  float w1s, w1c, w2s, w2c;
  __sincosf(-0.00306796158f * (float)tid, &w1s, &w1c);
  __sincosf(-0.00306796158f * (float)(tid + 256), &w2s, &w2c);
  Tw t0, t1, t2, t3;
  fft_tws(tid, t0, t1, t2, t3);
  const Tw i0 = conj_tw(t0), i1 = conj_tw(t1), i2 = conj_tw(t2), i3 = conj_tw(t3);
  const float2* zrow = z + ((size_t)blockIdx.x << 10);
  float2 mv[4], ssv[4];
#pragma unroll
  for (int j = 0; j < 4; ++j) {
    mv[j] = mean2[tid + (j << 8)];
    ssv[j] = sstd2[tid + (j << 8)];
  }
#pragma unroll
  for (int j = 0; j < 4; ++j) {
    const int n = tid + (j << 8);
    B[P2(n)] = zrow[n];
  }
  lds_barrier();
  combine_all(B, tid, w1c, w1s, w2c, w2s, wk1, wm1, wk2, wm2, wmid);
  stage4(B, A, 0, i0, false);
  stage4(A, B, 2, i1, false);
  stage4(B, A, 4, i2, false);
  stage4(A, B, 6, i3, false);
  float2 o0, o1, o2, o3;
  stage_nt_reg(B, o0, o1, o2, o3, false);
  const float inv = 1.0f / 1024.0f;
  float2* out2 = (float2*)out + ((size_t)blockIdx.x << 10);
  float2 oo;
  oo.x = fmaf(o0.x * inv, ssv[0].x, mv[0].x);
  oo.y = fmaf(o0.y * inv, ssv[0].y, mv[0].y);
  out2[tid] = oo;
  oo.x = fmaf(o1.x * inv, ssv[1].x, mv[1].x);
  oo.y = fmaf(o1.y * inv, ssv[1].y, mv[1].y);
  out2[tid + 256] = oo;
  oo.x = fmaf(o2.x * inv, ssv[2].x, mv[2].x);
  oo.y = fmaf(o2.y * inv, ssv[2].y, mv[2].y);
  out2[tid + 512] = oo;
  oo.x = fmaf(o3.x * inv, ssv[3].x, mv[3].x);
  oo.y = fmaf(o3.y * inv, ssv[3].y, mv[3].y);
  out2[tid + 768] = oo;
}

extern "C" void kernel_launch(void* const* d_in, const int* in_sizes, int n_in,
                              void* d_out, int out_size, void* d_ws, size_t ws_size,
                              hipStream_t stream) {
  const float* x = (const float*)d_in[0];
  const float* bb = (const float*)d_in[1];
  const float* gw = (const float*)d_in[2];
  const float* gb = (const float*)d_in[3];
  float* ws = (float*)d_ws;
  float* out = (float*)d_out;

  const bool split = ws_size >= (size_t)WS_END_SPLIT * sizeof(float);
  const bool cache = ws_size >= (size_t)WS_END_CACHE * sizeof(float);
  const bool part = ws_size >= (size_t)WS_END_GPART * sizeof(float);

  if (!part) {
    hipMemsetAsync((char*)d_ws + WS_GACC * sizeof(float), 0, (NB * NF) * sizeof(float), stream);
  }
  if (split) {
    kmoments_part<<<dim3(NB * 8, 2), dim3(256), 0, stream>>>(x, ws);
    kmoments_fin<<<dim3(256), dim3(256), 0, stream>>>(ws);
  } else {
    kmoments<<<dim3(NB * 8), dim3(256), 0, stream>>>(x, ws);
  }
  kspec<<<dim3(NB * 64), dim3(256), 0, stream>>>(x, ws,
      cache ? (float2*)(ws + WS_SPEC) : nullptr,
      part ? (ws + WS_GPART) : nullptr);
  kgate<<<dim3(NB), dim3(256), 0, stream>>>(ws, gw, gb, bb,
      part ? (ws + WS_GPART) : nullptr);
  if (cache) {
    kapply_z<<<dim3(NB * NC), dim3(256), 0, stream>>>((const float2*)(ws + WS_SPEC), out, ws);
  } else {
    kapply<<<dim3(NB * NC), dim3(256), 0, stream>>>(x, out, ws);
  }
}